// Round 1
// baseline (316.023 us; speedup 1.0000x reference)
//
#include <hip/hip_runtime.h>
#include <hip/hip_bf16.h>
#include <stdint.h>

#define BSZ 1024
#define KF 32768
#define SPLITK 8
#define KPER (KF / SPLITK)   // 4096
#define TEMP_INV 10.0f

typedef __bf16 bf16_t;
typedef bf16_t bf16x8 __attribute__((ext_vector_type(8)));
typedef float f32x4 __attribute__((ext_vector_type(4)));

__device__ __forceinline__ void async_copy16(const void* g, void* l) {
    __builtin_amdgcn_global_load_lds(
        (const __attribute__((address_space(1))) void*)g,
        (__attribute__((address_space(3))) void*)l, 16, 0, 0);
}

__device__ __forceinline__ unsigned short f2bf_bits(float x) {
    union { float f; uint32_t u; } t; t.f = x;
    uint32_t r = t.u + 0x7FFFu + ((t.u >> 16) & 1u);   // RN-even, finite inputs
    return (unsigned short)(r >> 16);
}

__device__ __forceinline__ float waveSum(float v) {
    for (int o = 32; o > 0; o >>= 1) v += __shfl_down(v, o);
    return v;
}
__device__ __forceinline__ float waveMax(float v) {
    for (int o = 32; o > 0; o >>= 1) v = fmaxf(v, __shfl_down(v, o));
    return v;
}
__device__ __forceinline__ float blockSum(float v, float* red, int tid) {
    v = waveSum(v);
    __syncthreads();
    if ((tid & 63) == 0) red[tid >> 6] = v;
    __syncthreads();
    return red[0] + red[1] + red[2] + red[3];
}
__device__ __forceinline__ float blockMax(float v, float* red, int tid) {
    v = waveMax(v);
    __syncthreads();
    if ((tid & 63) == 0) red[tid >> 6] = v;
    __syncthreads();
    return fmaxf(fmaxf(red[0], red[1]), fmaxf(red[2], red[3]));
}

// K1: per-row sum of squares (fp32, exact) + fp32->bf16 convert of raw features.
__global__ __launch_bounds__(256) void k_norm_convert(
    const float* __restrict__ f, bf16_t* __restrict__ fb, float* __restrict__ inv_norm) {
    int row = blockIdx.x, tid = threadIdx.x;
    const float4* src = (const float4*)(f + (size_t)row * KF);
    ushort4* dst = (ushort4*)((unsigned short*)fb + (size_t)row * KF);
    float ss = 0.f;
    for (int c = 0; c < 32; ++c) {
        int i4 = c * 256 + tid;
        float4 v = src[i4];
        ss += v.x * v.x + v.y * v.y + v.z * v.z + v.w * v.w;
        ushort4 pk;
        pk.x = f2bf_bits(v.x); pk.y = f2bf_bits(v.y);
        pk.z = f2bf_bits(v.z); pk.w = f2bf_bits(v.w);
        dst[i4] = pk;
    }
    __shared__ float red[4];
    float tot = blockSum(ss, red, tid);
    if (tid == 0) inv_norm[row] = 1.0f / fmaxf(sqrtf(tot), 1e-8f);
}

// K2: raw gram partials: partials[p] = Fb[rows] * Fb[cols]^T over k in [p*4096,(p+1)*4096)
// 128x128 tile, BK=32, 4 waves x (4x4 of 16x16x32 MFMA), global_load_lds width-16 staging.
__global__ __launch_bounds__(256) void k_gemm(
    const bf16_t* __restrict__ fb, float* __restrict__ partials) {
    __shared__ bf16_t Alds[128 * 32];
    __shared__ bf16_t Blds[128 * 32];
    int tid = threadIdx.x;
    int row0 = blockIdx.x * 128, col0 = blockIdx.y * 128;
    int p = blockIdx.z;
    int kbase = p * KPER;
    const bf16_t* Ag = fb + (size_t)row0 * KF;
    const bf16_t* Bg = fb + (size_t)col0 * KF;
    int lane = tid & 63, w = tid >> 6;
    int wrow = (w >> 1) * 64, wcol = (w & 1) * 64;
    int mrow = lane & 15, quad = lane >> 4;

    // staging indices: idx covers 512 chunks of 8 bf16 (16B); LDS layout [128][32] row-major
    int idx0 = tid, idx1 = tid + 256;
    int r0 = idx0 >> 2, kc0 = (idx0 & 3) * 8;
    int r1 = idx1 >> 2, kc1 = (idx1 & 3) * 8;

    f32x4 acc[4][4] = {};

    for (int kt = 0; kt < KPER / 32; ++kt) {
        int k0 = kbase + kt * 32;
        __syncthreads();
        async_copy16(Ag + (size_t)r0 * KF + k0 + kc0, &Alds[idx0 * 8]);
        async_copy16(Ag + (size_t)r1 * KF + k0 + kc1, &Alds[idx1 * 8]);
        async_copy16(Bg + (size_t)r0 * KF + k0 + kc0, &Blds[idx0 * 8]);
        async_copy16(Bg + (size_t)r1 * KF + k0 + kc1, &Blds[idx1 * 8]);
        __syncthreads();
        bf16x8 af[4], bfr[4];
#pragma unroll
        for (int mi = 0; mi < 4; ++mi)
            af[mi] = *(const bf16x8*)&Alds[(wrow + mi * 16 + mrow) * 32 + quad * 8];
#pragma unroll
        for (int ni = 0; ni < 4; ++ni)
            bfr[ni] = *(const bf16x8*)&Blds[(wcol + ni * 16 + mrow) * 32 + quad * 8];
#pragma unroll
        for (int mi = 0; mi < 4; ++mi)
#pragma unroll
            for (int ni = 0; ni < 4; ++ni)
                acc[mi][ni] = __builtin_amdgcn_mfma_f32_16x16x32_bf16(
                    af[mi], bfr[ni], acc[mi][ni], 0, 0, 0);
    }

    float* outp = partials + (size_t)p * BSZ * BSZ;
#pragma unroll
    for (int mi = 0; mi < 4; ++mi)
#pragma unroll
        for (int ni = 0; ni < 4; ++ni)
#pragma unroll
            for (int r = 0; r < 4; ++r) {
                int row = row0 + wrow + mi * 16 + quad * 4 + r;   // C/D: row=(lane>>4)*4+reg
                int col = col0 + wcol + ni * 16 + mrow;           //      col=lane&15
                outp[(size_t)row * BSZ + col] = acc[mi][ni][r];
            }
}

// K3: per-row loss. Sum split-K partials, scale by inv_norms * 10, online stats.
__global__ __launch_bounds__(256) void k_loss_rows(
    const float* __restrict__ partials, const float* __restrict__ inv_norm,
    const int* __restrict__ labels, float* __restrict__ rloss,
    float* __restrict__ rvalid, float* __restrict__ rcorr) {
    int i = blockIdx.x, tid = threadIdx.x;
    __shared__ float srow[BSZ];
    __shared__ float red[4];
    float inv_i = inv_norm[i];
    int lab_i = labels[i];

    for (int c = 0; c < 4; ++c) {
        int j = c * 256 + tid;
        float s = 0.f;
#pragma unroll
        for (int p2 = 0; p2 < SPLITK; ++p2)
            s += partials[(size_t)p2 * BSZ * BSZ + (size_t)i * BSZ + j];
        srow[j] = s * inv_i * inv_norm[j] * TEMP_INV;
    }
    __syncthreads();

    float lm = -3.0e38f;
    for (int c = 0; c < 4; ++c) {
        int j = c * 256 + tid;
        if (j != i) lm = fmaxf(lm, srow[j]);
    }
    float rowmax = blockMax(lm, red, tid);

    float pos_sum = 0.f, neg_sum = 0.f, mp = -3.0e38f, mn = -3.0e38f;
    for (int c = 0; c < 4; ++c) {
        int j = c * 256 + tid;
        if (j == i) continue;
        float s = srow[j];
        float e = expf(s - rowmax);
        if (labels[j] == lab_i) { pos_sum += e; mp = fmaxf(mp, s); }
        else                    { neg_sum += e; mn = fmaxf(mn, s); }
    }
    float ps = blockSum(pos_sum, red, tid);
    float ns = blockSum(neg_sum, red, tid);
    float mpa = blockMax(mp, red, tid);
    float mna = blockMax(mn, red, tid);
    if (tid == 0) {
        bool valid = (mpa > -1.0e37f) && (mna > -1.0e37f);
        rloss[i]  = valid ? (logf(ns) - logf(ps)) : 0.f;
        rvalid[i] = valid ? 1.f : 0.f;
        rcorr[i]  = (valid && (mpa > mna)) ? 1.f : 0.f;
    }
}

// K4: final scalar reduce -> d_out[0]=loss, d_out[1]=accuracy
__global__ __launch_bounds__(256) void k_final(
    const float* __restrict__ rloss, const float* __restrict__ rvalid,
    const float* __restrict__ rcorr, float* __restrict__ out) {
    __shared__ float red[4];
    int tid = threadIdx.x;
    float sl = 0.f, sv = 0.f, sc = 0.f;
    for (int c = 0; c < 4; ++c) {
        int j = c * 256 + tid;
        sl += rloss[j]; sv += rvalid[j]; sc += rcorr[j];
    }
    sl = blockSum(sl, red, tid);
    sv = blockSum(sv, red, tid);
    sc = blockSum(sc, red, tid);
    if (tid == 0) {
        out[0] = (sv > 0.f) ? sl / fmaxf(sv, 1.f) : 0.f;
        out[1] = (sv > 0.f) ? sc / fmaxf(sv, 1.f) : 0.5f;
    }
}

extern "C" void kernel_launch(void* const* d_in, const int* in_sizes, int n_in,
                              void* d_out, int out_size, void* d_ws, size_t ws_size,
                              hipStream_t stream) {
    const float* feats = (const float*)d_in[0];
    const int* labels = (const int*)d_in[1];
    float* out = (float*)d_out;
    char* ws = (char*)d_ws;

    // ws layout: [0,64MB) bf16 features | [64MB,96MB) 8 gram partials | then small arrays
    bf16_t* fb       = (bf16_t*)ws;
    float* partials  = (float*)(ws + (size_t)64 * 1024 * 1024);
    float* inv_norm  = (float*)(ws + (size_t)96 * 1024 * 1024);
    float* rloss     = inv_norm + BSZ;
    float* rvalid    = rloss + BSZ;
    float* rcorr     = rvalid + BSZ;

    k_norm_convert<<<BSZ, 256, 0, stream>>>(feats, fb, inv_norm);
    k_gemm<<<dim3(8, 8, SPLITK), 256, 0, stream>>>(fb, partials);
    k_loss_rows<<<BSZ, 256, 0, stream>>>(partials, inv_norm, labels, rloss, rvalid, rcorr);
    k_final<<<1, 256, 0, stream>>>(rloss, rvalid, rcorr, out);
}

// Round 2
// 310.041 us; speedup vs baseline: 1.0193x; 1.0193x over previous
//
#include <hip/hip_runtime.h>
#include <hip/hip_bf16.h>
#include <stdint.h>

#define BSZ 1024
#define KF 32768
#define SPLITK 16
#define KPER (KF / SPLITK)   // 2048
#define BK 64
#define TEMP_INV 10.0f

typedef __bf16 bf16_t;
typedef bf16_t bf16x8 __attribute__((ext_vector_type(8)));
typedef float f32x4 __attribute__((ext_vector_type(4)));

__device__ __forceinline__ void async_copy16(const void* g, void* l) {
    __builtin_amdgcn_global_load_lds(
        (const __attribute__((address_space(1))) void*)g,
        (__attribute__((address_space(3))) void*)l, 16, 0, 0);
}

__device__ __forceinline__ unsigned short f2bf_bits(float x) {
    union { float f; uint32_t u; } t; t.f = x;
    uint32_t r = t.u + 0x7FFFu + ((t.u >> 16) & 1u);   // RN-even, finite inputs
    return (unsigned short)(r >> 16);
}
__device__ __forceinline__ float bf2f(unsigned short b) {
    union { uint32_t u; float f; } t; t.u = ((uint32_t)b) << 16; return t.f;
}

__device__ __forceinline__ float waveSum(float v) {
    for (int o = 32; o > 0; o >>= 1) v += __shfl_down(v, o);
    return v;
}
__device__ __forceinline__ float waveMax(float v) {
    for (int o = 32; o > 0; o >>= 1) v = fmaxf(v, __shfl_down(v, o));
    return v;
}
__device__ __forceinline__ float blockSum(float v, float* red, int tid) {
    v = waveSum(v);
    __syncthreads();
    if ((tid & 63) == 0) red[tid >> 6] = v;
    __syncthreads();
    return red[0] + red[1] + red[2] + red[3];
}
__device__ __forceinline__ float blockMax(float v, float* red, int tid) {
    v = waveMax(v);
    __syncthreads();
    if ((tid & 63) == 0) red[tid >> 6] = v;
    __syncthreads();
    return fmaxf(fmaxf(red[0], red[1]), fmaxf(red[2], red[3]));
}

// K1: per-row sum of squares (fp32, exact) + fp32->bf16 convert of raw features.
__global__ __launch_bounds__(256) void k_norm_convert(
    const float* __restrict__ f, bf16_t* __restrict__ fb, float* __restrict__ inv_norm) {
    int row = blockIdx.x, tid = threadIdx.x;
    const float4* src = (const float4*)(f + (size_t)row * KF);
    ushort4* dst = (ushort4*)((unsigned short*)fb + (size_t)row * KF);
    float ss = 0.f;
    for (int c = 0; c < 32; ++c) {
        int i4 = c * 256 + tid;
        float4 v = src[i4];
        ss += v.x * v.x + v.y * v.y + v.z * v.z + v.w * v.w;
        ushort4 pk;
        pk.x = f2bf_bits(v.x); pk.y = f2bf_bits(v.y);
        pk.z = f2bf_bits(v.z); pk.w = f2bf_bits(v.w);
        dst[i4] = pk;
    }
    __shared__ float red[4];
    float tot = blockSum(ss, red, tid);
    if (tid == 0) inv_norm[row] = 1.0f / fmaxf(sqrtf(tot), 1e-8f);
}

// K2: raw gram partials over symmetric tiles (bi>=bj), mirrored epilogue.
// 128x128 tile, BK=64, XOR-8 LDS swizzle (2-way banks = free), bf16 partials.
__global__ __launch_bounds__(256) void k_gemm(
    const bf16_t* __restrict__ fb, unsigned short* __restrict__ partials) {
    __shared__ bf16_t Alds[128 * BK];
    __shared__ bf16_t Blds[128 * BK];
    int tid = threadIdx.x;

    // decode triangular tile index: blockIdx.x in [0,36) -> (bi >= bj)
    int t = blockIdx.x;
    int bi = 0, accu = 0;
    while (accu + bi + 1 <= t) { accu += bi + 1; ++bi; }
    int bj = t - accu;
    int row0 = bi * 128, col0 = bj * 128;
    int p = blockIdx.y;
    int kbase = p * KPER;

    const bf16_t* Ag = fb + (size_t)row0 * KF;
    const bf16_t* Bg = fb + (size_t)col0 * KF;
    int lane = tid & 63, w = tid >> 6;
    int wrow = (w >> 1) * 64, wcol = (w & 1) * 64;
    int mrow = lane & 15, quad = lane >> 4;

    // staging: 1024 chunks of 16B per matrix; LDS chunk idx holds global
    // column-group g = (idx&7) ^ ((idx>>3)&7)  (XOR swizzle kills bank conflicts)
    int r_st[4], g_st[4];
#pragma unroll
    for (int c = 0; c < 4; ++c) {
        int idx = c * 256 + tid;
        r_st[c] = idx >> 3;
        g_st[c] = (idx & 7) ^ (r_st[c] & 7);
    }

    f32x4 acc[4][4] = {};

    for (int kt = 0; kt < KPER / BK; ++kt) {
        int k0 = kbase + kt * BK;
        __syncthreads();
#pragma unroll
        for (int c = 0; c < 4; ++c) {
            int idx = c * 256 + tid;
            async_copy16(Ag + (size_t)r_st[c] * KF + k0 + g_st[c] * 8, &Alds[idx * 8]);
            async_copy16(Bg + (size_t)r_st[c] * KF + k0 + g_st[c] * 8, &Blds[idx * 8]);
        }
        __syncthreads();
#pragma unroll
        for (int ks = 0; ks < 2; ++ks) {
            bf16x8 af[4], bfr[4];
#pragma unroll
            for (int mi = 0; mi < 4; ++mi) {
                int row = wrow + mi * 16 + mrow;
                int cc = (ks * 4 + quad) ^ (row & 7);
                af[mi] = *(const bf16x8*)&Alds[row * BK + cc * 8];
            }
#pragma unroll
            for (int ni = 0; ni < 4; ++ni) {
                int row = wcol + ni * 16 + mrow;
                int cc = (ks * 4 + quad) ^ (row & 7);
                bfr[ni] = *(const bf16x8*)&Blds[row * BK + cc * 8];
            }
#pragma unroll
            for (int mi = 0; mi < 4; ++mi)
#pragma unroll
                for (int ni = 0; ni < 4; ++ni)
                    acc[mi][ni] = __builtin_amdgcn_mfma_f32_16x16x32_bf16(
                        af[mi], bfr[ni], acc[mi][ni], 0, 0, 0);
        }
    }

    unsigned short* outp = partials + (size_t)p * BSZ * BSZ;
    // normal write: coalesced 2B stores (col = lane-contiguous)
#pragma unroll
    for (int mi = 0; mi < 4; ++mi)
#pragma unroll
        for (int ni = 0; ni < 4; ++ni)
#pragma unroll
            for (int r = 0; r < 4; ++r) {
                int row = row0 + wrow + mi * 16 + quad * 4 + r;   // C/D: row=(lane>>4)*4+reg
                int col = col0 + wcol + ni * 16 + mrow;           //      col=lane&15
                outp[(size_t)row * BSZ + col] = f2bf_bits(acc[mi][ni][r]);
            }
    if (bi != bj) {
        // mirrored write: 4 consecutive rows -> ushort4 (8B) stores
#pragma unroll
        for (int mi = 0; mi < 4; ++mi)
#pragma unroll
            for (int ni = 0; ni < 4; ++ni) {
                int rowm = col0 + wcol + ni * 16 + mrow;          // transposed row
                int colm = row0 + wrow + mi * 16 + quad * 4;      // transposed col base
                ushort4 v;
                v.x = f2bf_bits(acc[mi][ni][0]);
                v.y = f2bf_bits(acc[mi][ni][1]);
                v.z = f2bf_bits(acc[mi][ni][2]);
                v.w = f2bf_bits(acc[mi][ni][3]);
                *(ushort4*)&outp[(size_t)rowm * BSZ + colm] = v;
            }
    }
}

// K3: per-row loss. Sum split-K bf16 partials, scale by inv_norms * 10, stats.
__global__ __launch_bounds__(256) void k_loss_rows(
    const unsigned short* __restrict__ partials, const float* __restrict__ inv_norm,
    const int* __restrict__ labels, float* __restrict__ rloss,
    float* __restrict__ rvalid, float* __restrict__ rcorr) {
    int i = blockIdx.x, tid = threadIdx.x;
    __shared__ float srow[BSZ];
    __shared__ float red[4];
    float inv_i = inv_norm[i];
    int lab_i = labels[i];

    for (int c = 0; c < 4; ++c) {
        int j = c * 256 + tid;
        float s = 0.f;
#pragma unroll
        for (int p2 = 0; p2 < SPLITK; ++p2)
            s += bf2f(partials[(size_t)p2 * BSZ * BSZ + (size_t)i * BSZ + j]);
        srow[j] = s * inv_i * inv_norm[j] * TEMP_INV;
    }
    __syncthreads();

    float lm = -3.0e38f;
    for (int c = 0; c < 4; ++c) {
        int j = c * 256 + tid;
        if (j != i) lm = fmaxf(lm, srow[j]);
    }
    float rowmax = blockMax(lm, red, tid);

    float pos_sum = 0.f, neg_sum = 0.f, mp = -3.0e38f, mn = -3.0e38f;
    for (int c = 0; c < 4; ++c) {
        int j = c * 256 + tid;
        if (j == i) continue;
        float s = srow[j];
        float e = expf(s - rowmax);
        if (labels[j] == lab_i) { pos_sum += e; mp = fmaxf(mp, s); }
        else                    { neg_sum += e; mn = fmaxf(mn, s); }
    }
    float ps = blockSum(pos_sum, red, tid);
    float ns = blockSum(neg_sum, red, tid);
    float mpa = blockMax(mp, red, tid);
    float mna = blockMax(mn, red, tid);
    if (tid == 0) {
        bool valid = (mpa > -1.0e37f) && (mna > -1.0e37f);
        rloss[i]  = valid ? (logf(ns) - logf(ps)) : 0.f;
        rvalid[i] = valid ? 1.f : 0.f;
        rcorr[i]  = (valid && (mpa > mna)) ? 1.f : 0.f;
    }
}

// K4: final scalar reduce -> d_out[0]=loss, d_out[1]=accuracy
__global__ __launch_bounds__(256) void k_final(
    const float* __restrict__ rloss, const float* __restrict__ rvalid,
    const float* __restrict__ rcorr, float* __restrict__ out) {
    __shared__ float red[4];
    int tid = threadIdx.x;
    float sl = 0.f, sv = 0.f, sc = 0.f;
    for (int c = 0; c < 4; ++c) {
        int j = c * 256 + tid;
        sl += rloss[j]; sv += rvalid[j]; sc += rcorr[j];
    }
    sl = blockSum(sl, red, tid);
    sv = blockSum(sv, red, tid);
    sc = blockSum(sc, red, tid);
    if (tid == 0) {
        out[0] = (sv > 0.f) ? sl / fmaxf(sv, 1.f) : 0.f;
        out[1] = (sv > 0.f) ? sc / fmaxf(sv, 1.f) : 0.5f;
    }
}

extern "C" void kernel_launch(void* const* d_in, const int* in_sizes, int n_in,
                              void* d_out, int out_size, void* d_ws, size_t ws_size,
                              hipStream_t stream) {
    const float* feats = (const float*)d_in[0];
    const int* labels = (const int*)d_in[1];
    float* out = (float*)d_out;
    char* ws = (char*)d_ws;

    // ws layout: [0,64MB) bf16 features | [64MB,96MB) 16 bf16 gram partials | small arrays
    bf16_t* fb               = (bf16_t*)ws;
    unsigned short* partials = (unsigned short*)(ws + (size_t)64 * 1024 * 1024);
    float* inv_norm          = (float*)(ws + (size_t)96 * 1024 * 1024);
    float* rloss             = inv_norm + BSZ;
    float* rvalid            = rloss + BSZ;
    float* rcorr             = rvalid + BSZ;

    k_norm_convert<<<BSZ, 256, 0, stream>>>(feats, fb, inv_norm);
    k_gemm<<<dim3(36, SPLITK), 256, 0, stream>>>(fb, partials);
    k_loss_rows<<<BSZ, 256, 0, stream>>>(partials, inv_norm, labels, rloss, rvalid, rcorr);
    k_final<<<1, 256, 0, stream>>>(rloss, rvalid, rcorr, out);
}

// Round 3
// 270.361 us; speedup vs baseline: 1.1689x; 1.1468x over previous
//
#include <hip/hip_runtime.h>
#include <hip/hip_bf16.h>
#include <stdint.h>

#define BSZ 1024
#define KF 32768            // feature length (elements == bytes in fp8)
#define SPLITK 32
#define KPER (KF / SPLITK)  // 1024
#define BKB 128             // K elements (bytes) staged per iter
#define TEMP_INV 10.0f

typedef float f32x4 __attribute__((ext_vector_type(4)));

__device__ __forceinline__ void async_copy16(const void* g, void* l) {
    __builtin_amdgcn_global_load_lds(
        (const __attribute__((address_space(1))) void*)g,
        (__attribute__((address_space(3))) void*)l, 16, 0, 0);
}

__device__ __forceinline__ unsigned short f2bf_bits(float x) {
    union { float f; uint32_t u; } t; t.f = x;
    uint32_t r = t.u + 0x7FFFu + ((t.u >> 16) & 1u);   // RN-even, finite inputs
    return (unsigned short)(r >> 16);
}
__device__ __forceinline__ float bf2f(unsigned short b) {
    union { uint32_t u; float f; } t; t.u = ((uint32_t)b) << 16; return t.f;
}

__device__ __forceinline__ float waveSum(float v) {
    for (int o = 32; o > 0; o >>= 1) v += __shfl_down(v, o);
    return v;
}
__device__ __forceinline__ float waveMax(float v) {
    for (int o = 32; o > 0; o >>= 1) v = fmaxf(v, __shfl_down(v, o));
    return v;
}
__device__ __forceinline__ float blockSum(float v, float* red, int tid) {
    v = waveSum(v);
    __syncthreads();
    if ((tid & 63) == 0) red[tid >> 6] = v;
    __syncthreads();
    return red[0] + red[1] + red[2] + red[3];
}
__device__ __forceinline__ float blockMax(float v, float* red, int tid) {
    v = waveMax(v);
    __syncthreads();
    if ((tid & 63) == 0) red[tid >> 6] = v;
    __syncthreads();
    return fmaxf(fmaxf(red[0], red[1]), fmaxf(red[2], red[3]));
}

// K1: per-row sum of squares (fp32, exact) + fp32->fp8(e4m3) convert.
__global__ __launch_bounds__(256) void k_norm_convert(
    const float* __restrict__ f, unsigned char* __restrict__ f8,
    float* __restrict__ inv_norm) {
    int row = blockIdx.x, tid = threadIdx.x;
    const float4* src = (const float4*)(f + (size_t)row * KF);
    int4* dst = (int4*)(f8 + (size_t)row * KF);
    float ss = 0.f;
    for (int o = 0; o < 8; ++o) {
        int base4 = o * 1024 + tid * 4;
        int4 pk;
        int* pkp = &pk.x;
#pragma unroll
        for (int q = 0; q < 4; ++q) {
            float4 v = src[base4 + q];
            ss += v.x * v.x + v.y * v.y + v.z * v.z + v.w * v.w;
            int wd = __builtin_amdgcn_cvt_pk_fp8_f32(v.x, v.y, 0, false);
            wd = __builtin_amdgcn_cvt_pk_fp8_f32(v.z, v.w, wd, true);
            pkp[q] = wd;
        }
        dst[o * 256 + tid] = pk;
    }
    __shared__ float red[4];
    float tot = blockSum(ss, red, tid);
    if (tid == 0) inv_norm[row] = 1.0f / fmaxf(sqrtf(tot), 1e-8f);
}

// K2: fp8 gram partials over symmetric tiles (bi>=bj), mirrored epilogue.
// 128x128 tile, K=128/iter, XOR-8 16B-chunk swizzle, bf16 partials.
__global__ __launch_bounds__(256) void k_gemm(
    const unsigned char* __restrict__ f8, unsigned short* __restrict__ partials) {
    __shared__ unsigned char Alds[128 * BKB];   // 16 KB
    __shared__ unsigned char Blds[128 * BKB];   // 16 KB
    int tid = threadIdx.x;

    int t = blockIdx.x;                 // triangular tile: bi >= bj
    int bi = 0, accu = 0;
    while (accu + bi + 1 <= t) { accu += bi + 1; ++bi; }
    int bj = t - accu;
    int row0 = bi * 128, col0 = bj * 128;
    int p = blockIdx.y;
    size_t kbase = (size_t)p * KPER;

    const unsigned char* Ag = f8 + (size_t)row0 * KF;
    const unsigned char* Bg = f8 + (size_t)col0 * KF;
    int lane = tid & 63, w = tid >> 6;
    int wrow = (w >> 1) * 64, wcol = (w & 1) * 64;
    int mrow = lane & 15, quad = lane >> 4;

    // staging: 1024 chunks of 16B per matrix; LDS slot s of row r holds
    // global chunk s^(r&7)  (XOR swizzle -> 2-way banks on read = free)
    int r_st[4], g_st[4];
#pragma unroll
    for (int c = 0; c < 4; ++c) {
        int idx = c * 256 + tid;
        r_st[c] = idx >> 3;
        g_st[c] = (idx & 7) ^ (r_st[c] & 7);
    }

    f32x4 acc[4][4] = {};

    for (int kt = 0; kt < KPER / BKB; ++kt) {   // 8 iters
        size_t k0 = kbase + (size_t)kt * BKB;
        __syncthreads();
#pragma unroll
        for (int c = 0; c < 4; ++c) {
            int idx = c * 256 + tid;
            async_copy16(Ag + (size_t)r_st[c] * KF + k0 + g_st[c] * 16, &Alds[idx * 16]);
            async_copy16(Bg + (size_t)r_st[c] * KF + k0 + g_st[c] * 16, &Blds[idx * 16]);
        }
        __syncthreads();
#pragma unroll
        for (int ks = 0; ks < 4; ++ks) {        // 4 x K=32 per staged K=128
            long av[4], bv[4];
            int chunk = ks * 2 + (quad >> 1);
            int sub = (quad & 1) * 8;
#pragma unroll
            for (int mi = 0; mi < 4; ++mi) {
                int row = wrow + mi * 16 + mrow;
                av[mi] = *(const long*)&Alds[row * BKB + (chunk ^ (row & 7)) * 16 + sub];
            }
#pragma unroll
            for (int ni = 0; ni < 4; ++ni) {
                int row = wcol + ni * 16 + mrow;
                bv[ni] = *(const long*)&Blds[row * BKB + (chunk ^ (row & 7)) * 16 + sub];
            }
#pragma unroll
            for (int mi = 0; mi < 4; ++mi)
#pragma unroll
                for (int ni = 0; ni < 4; ++ni)
                    acc[mi][ni] = __builtin_amdgcn_mfma_f32_16x16x32_fp8_fp8(
                        av[mi], bv[ni], acc[mi][ni], 0, 0, 0);
        }
    }

    unsigned short* outp = partials + (size_t)p * BSZ * BSZ;
#pragma unroll
    for (int mi = 0; mi < 4; ++mi)
#pragma unroll
        for (int ni = 0; ni < 4; ++ni)
#pragma unroll
            for (int r = 0; r < 4; ++r) {
                int row = row0 + wrow + mi * 16 + quad * 4 + r;   // C/D: row=(lane>>4)*4+reg
                int col = col0 + wcol + ni * 16 + mrow;           //      col=lane&15
                outp[(size_t)row * BSZ + col] = f2bf_bits(acc[mi][ni][r]);
            }
    if (bi != bj) {
#pragma unroll
        for (int mi = 0; mi < 4; ++mi)
#pragma unroll
            for (int ni = 0; ni < 4; ++ni) {
                int rowm = col0 + wcol + ni * 16 + mrow;
                int colm = row0 + wrow + mi * 16 + quad * 4;
                ushort4 v;
                v.x = f2bf_bits(acc[mi][ni][0]);
                v.y = f2bf_bits(acc[mi][ni][1]);
                v.z = f2bf_bits(acc[mi][ni][2]);
                v.w = f2bf_bits(acc[mi][ni][3]);
                *(ushort4*)&outp[(size_t)rowm * BSZ + colm] = v;
            }
    }
}

// K3: per-row loss. Sum split-K bf16 partials (ushort4 vec), scale, stats.
__global__ __launch_bounds__(256) void k_loss_rows(
    const unsigned short* __restrict__ partials, const float* __restrict__ inv_norm,
    const int* __restrict__ labels, float* __restrict__ rloss,
    float* __restrict__ rvalid, float* __restrict__ rcorr) {
    int i = blockIdx.x, tid = threadIdx.x;
    __shared__ float srow[BSZ];
    __shared__ int slab[BSZ];
    __shared__ float red[4];
    for (int c = 0; c < 4; ++c) slab[c * 256 + tid] = labels[c * 256 + tid];
    float inv_i = inv_norm[i];

    int j4 = tid * 4;
    float sx = 0.f, sy = 0.f, sz = 0.f, sw = 0.f;
#pragma unroll
    for (int p2 = 0; p2 < SPLITK; ++p2) {
        ushort4 v = *(const ushort4*)&partials[(size_t)p2 * BSZ * BSZ + (size_t)i * BSZ + j4];
        sx += bf2f(v.x); sy += bf2f(v.y); sz += bf2f(v.z); sw += bf2f(v.w);
    }
    float4 invj = *(const float4*)&inv_norm[j4];
    srow[j4 + 0] = sx * inv_i * invj.x * TEMP_INV;
    srow[j4 + 1] = sy * inv_i * invj.y * TEMP_INV;
    srow[j4 + 2] = sz * inv_i * invj.z * TEMP_INV;
    srow[j4 + 3] = sw * inv_i * invj.w * TEMP_INV;
    __syncthreads();

    int lab_i = slab[i];
    float lm = -3.0e38f;
    for (int c = 0; c < 4; ++c) {
        int j = c * 256 + tid;
        if (j != i) lm = fmaxf(lm, srow[j]);
    }
    float rowmax = blockMax(lm, red, tid);

    float pos_sum = 0.f, neg_sum = 0.f, mp = -3.0e38f, mn = -3.0e38f;
    for (int c = 0; c < 4; ++c) {
        int j = c * 256 + tid;
        if (j == i) continue;
        float s = srow[j];
        float e = expf(s - rowmax);
        if (slab[j] == lab_i) { pos_sum += e; mp = fmaxf(mp, s); }
        else                  { neg_sum += e; mn = fmaxf(mn, s); }
    }
    float ps = blockSum(pos_sum, red, tid);
    float ns = blockSum(neg_sum, red, tid);
    float mpa = blockMax(mp, red, tid);
    float mna = blockMax(mn, red, tid);
    if (tid == 0) {
        bool valid = (mpa > -1.0e37f) && (mna > -1.0e37f);
        rloss[i]  = valid ? (logf(ns) - logf(ps)) : 0.f;
        rvalid[i] = valid ? 1.f : 0.f;
        rcorr[i]  = (valid && (mpa > mna)) ? 1.f : 0.f;
    }
}

// K4: final scalar reduce -> d_out[0]=loss, d_out[1]=accuracy
__global__ __launch_bounds__(256) void k_final(
    const float* __restrict__ rloss, const float* __restrict__ rvalid,
    const float* __restrict__ rcorr, float* __restrict__ out) {
    __shared__ float red[4];
    int tid = threadIdx.x;
    float sl = 0.f, sv = 0.f, sc = 0.f;
    for (int c = 0; c < 4; ++c) {
        int j = c * 256 + tid;
        sl += rloss[j]; sv += rvalid[j]; sc += rcorr[j];
    }
    sl = blockSum(sl, red, tid);
    sv = blockSum(sv, red, tid);
    sc = blockSum(sc, red, tid);
    if (tid == 0) {
        out[0] = (sv > 0.f) ? sl / fmaxf(sv, 1.f) : 0.f;
        out[1] = (sv > 0.f) ? sc / fmaxf(sv, 1.f) : 0.5f;
    }
}

extern "C" void kernel_launch(void* const* d_in, const int* in_sizes, int n_in,
                              void* d_out, int out_size, void* d_ws, size_t ws_size,
                              hipStream_t stream) {
    const float* feats = (const float*)d_in[0];
    const int* labels = (const int*)d_in[1];
    float* out = (float*)d_out;
    char* ws = (char*)d_ws;

    // ws: [0,32MB) fp8 features | [32MB,96MB) 32 bf16 gram partials | small arrays
    unsigned char* f8        = (unsigned char*)ws;
    unsigned short* partials = (unsigned short*)(ws + (size_t)32 * 1024 * 1024);
    float* inv_norm          = (float*)(ws + (size_t)96 * 1024 * 1024);
    float* rloss             = inv_norm + BSZ;
    float* rvalid            = rloss + BSZ;
    float* rcorr             = rvalid + BSZ;

    k_norm_convert<<<BSZ, 256, 0, stream>>>(feats, f8, inv_norm);
    k_gemm<<<dim3(36, SPLITK), 256, 0, stream>>>(f8, partials);
    k_loss_rows<<<BSZ, 256, 0, stream>>>(partials, inv_norm, labels, rloss, rvalid, rcorr);
    k_final<<<1, 256, 0, stream>>>(rloss, rvalid, rcorr, out);
}